// Round 9
// baseline (357.300 us; speedup 1.0000x reference)
//
#include <hip/hip_runtime.h>
#include <hip/hip_bf16.h>

// RNN_41807211659578 R9: R5 structure (3 barriers, WRITE~0, best known 252us)
// + WYA/YBG (y pre-packed fp8 in global, vel folded into per-agent weights)
// + exactly 57 GRU weight i64 pinned "+a" (114 <= 128 AGPR file), MLP weights
// streamed from L2 inside their phases.

typedef unsigned short u16;
typedef unsigned int u32;
typedef unsigned char u8;
typedef long i64;
typedef __attribute__((ext_vector_type(4))) float f32x4;

#define MFMA_F8(acc, a, b) (acc) = __builtin_amdgcn_mfma_f32_16x16x32_fp8_fp8((i64)(a), (i64)(b), (acc), 0, 0, 0)

__device__ __forceinline__ void pinA(i64& x) { asm volatile("" : "+a"(x)); }

__device__ __forceinline__ u8 f2e4(float v) {
  return (u8)(__builtin_amdgcn_cvt_pk_fp8_f32(v, 0.f, 0, false) & 0xff);
}
__device__ __forceinline__ u32 pk4(float a, float b, float c, float d) {
  u32 p = (u32)__builtin_amdgcn_cvt_pk_fp8_f32(a, b, 0, false);
  return (u32)__builtin_amdgcn_cvt_pk_fp8_f32(c, d, (int)p, true);
}
__device__ __forceinline__ float sigf(float x) {
  return __builtin_amdgcn_rcpf(1.f + __expf(-x));
}
__device__ __forceinline__ float tanh_fast(float x) {
  return 1.f - 2.f * __builtin_amdgcn_rcpf(1.f + __expf(2.f * x));
}

// ---- workspace layout ----
constexpr int E0 = 2 * 384 * 352;      // W0cat [g][384][352] fp8
constexpr int E1 = E0 + 2 * 384 * 256; // W1cat [g][384][256]
constexpr int E2 = E1 + 2 * 128 * 128; // Wn0 (Whh0 n-rows)
constexpr int E3 = E2 + 2 * 128 * 128; // Wn1
constexpr int E4 = E3 + 2 * 128 * 128; // Wm1 (MLP W1)
constexpr int E5 = E4 + 2 * 128 * 128; // Wm2 (MLP W2)
constexpr int NBIAS = 2048;
constexpr int TOTAL = E5 + NBIAS + 4;
constexpr int WB_BYTE_OFF = 16384;

constexpr int WYA_REL = E5;                      // per-agent folded y-weights [23][384][96]
constexpr int YBG_REL = WYA_REL + 23 * 384 * 96; // packed y fp8 [48][256][96]
constexpr int NA1 = TOTAL;
constexpr int NA2 = NA1 + 23 * 384 * 96;
constexpr int NA3 = NA2 + 48 * 256 * 96;

__global__ void prep_kernel(const float* __restrict__ states,
                            const float* __restrict__ Wih0, const float* __restrict__ Whh0,
                            const float* __restrict__ bih0, const float* __restrict__ bhh0,
                            const float* __restrict__ Wih1, const float* __restrict__ Whh1,
                            const float* __restrict__ bih1, const float* __restrict__ bhh1,
                            const float* __restrict__ W1, const float* __restrict__ W2,
                            u8* __restrict__ wb, float* __restrict__ wsf) {
  for (int idx = blockIdx.x * blockDim.x + threadIdx.x; idx < NA3;
       idx += gridDim.x * blockDim.x) {
    if (idx < E0) {
      int g = idx / 135168;
      int r = idx - g * 135168;
      int j = r / 352;
      int k = r - j * 352;
      const float* wi = Wih0 + (g * 384 + j) * 222;
      float v;
      if (k < 94) v = wi[k];
      else if (k < 96) v = 0.f;
      else if (k < 224) v = wi[k - 2];
      else v = Whh0[(g * 384 + j) * 128 + (k - 224)];
      wb[idx] = f2e4(v);
    } else if (idx < E1) {
      int q = idx - E0;
      int g = q / 98304;
      int r = q - g * 98304;
      int j = r >> 8;
      int k = r & 255;
      float v = (k < 128) ? Wih1[(g * 384 + j) * 128 + k]
                          : Whh1[(g * 384 + j) * 128 + (k - 128)];
      wb[idx] = f2e4(v);
    } else if (idx < E2) {
      int q = idx - E1; int g = q >> 14; int r = q & 16383; int j = r >> 7; int k = r & 127;
      wb[idx] = f2e4(Whh0[(g * 384 + 256 + j) * 128 + k]);
    } else if (idx < E3) {
      int q = idx - E2; int g = q >> 14; int r = q & 16383; int j = r >> 7; int k = r & 127;
      wb[idx] = f2e4(Whh1[(g * 384 + 256 + j) * 128 + k]);
    } else if (idx < E4) {
      int q = idx - E3; int g = q >> 14; int r = q & 16383; int j = r >> 7; int k = r & 127;
      wb[idx] = f2e4(W1[(g * 128 + j) * 128 + k]);
    } else if (idx < E5) {
      int q = idx - E4; int g = q >> 14; int r = q & 16383; int j = r >> 7; int k = r & 127;
      wb[idx] = f2e4(W2[(g * 128 + j) * 128 + k]);
    } else if (idx < E5 + NBIAS) {
      int q = idx - E5;
      float v;
      if (q < 512)       { int g = q >> 8, j = q & 255;              v = bih0[g*384 + j] + bhh0[g*384 + j]; }
      else if (q < 768)  { int p = q - 512;  int g = p >> 7, j = p & 127; v = bih0[g*384 + 256 + j]; }
      else if (q < 1024) { int p = q - 768;  int g = p >> 7, j = p & 127; v = bhh0[g*384 + 256 + j]; }
      else if (q < 1536) { int p = q - 1024; int g = p >> 8, j = p & 255; v = bih1[g*384 + j] + bhh1[g*384 + j]; }
      else if (q < 1792) { int p = q - 1536; int g = p >> 7, j = p & 127; v = bih1[g*384 + 256 + j]; }
      else               { int p = q - 1792; int g = p >> 7, j = p & 127; v = bhh1[g*384 + 256 + j]; }
      wsf[4 + q] = v;
    } else if (idx < TOTAL) {
      wsf[idx - (E5 + NBIAS)] = 0.f;
    } else if (idx < NA2) {
      // WYA: per-agent folded y-weights [a][j][k], k<96
      int q = idx - NA1;
      int a = q / 36864;
      int r = q - a * 36864;
      int j = r / 96;
      int k = r - j * 96;
      const float* wi = Wih0 + (((a >= 12) ? 1 : 0) * 384 + j) * 222;
      float v = (k < 92) ? wi[2 + k] : 0.f;
      if (k == a * 4 + 2) v += wi[0];
      if (k == a * 4 + 3) v += wi[1];
      wb[WYA_REL + q] = f2e4(v);
    } else {
      // YBG: packed y fp8 [t][row][k], k<96
      int q = idx - NA2;
      int t = q / 24576;
      int r = q - t * 24576;
      int row = r / 96;
      int k = r - row * 96;
      float v = (k < 92) ? states[((size_t)t * 256 + row) * 92 + k] : 0.f;
      wb[YBG_REL + q] = f2e4(v);
    }
  }
}

__global__ __launch_bounds__(512, 2) __attribute__((amdgpu_waves_per_eu(2, 2)))
void rnn_kernel(const float* __restrict__ states,
                const u8* __restrict__ wb,
                float* __restrict__ wsf,
                const float* __restrict__ b1g,
                const float* __restrict__ b2g,
                const float* __restrict__ Wmg,
                const float* __restrict__ bmg) {
  const int blk = blockIdx.x;
  const int g = (blk < 96) ? 0 : 1;
  const int r0 = (g == 0) ? (blk * 32) : ((blk - 96) * 32);
  const int aAg = (g == 0 ? 0 : 12) + (r0 >> 8);
  const int b0 = r0 & 255;

  const int tid = threadIdx.x;
  const int wid = tid >> 6;
  const int ln = tid & 63;
  const int j_in = ln & 15;
  const int kq = ln >> 4;
  const int c0 = wid * 16 + kq * 4;
  const int jh = wid * 16 + j_in;

  __shared__ __align__(16) u8 h0b[2][32 * 136];
  __shared__ __align__(16) u8 h1b[2][32 * 136];
  __shared__ __align__(16) u8 d1b[32 * 136];
  __shared__ __align__(16) u8 d2b[32 * 136];
  __shared__ __align__(16) float bias[1536];
  __shared__ float dmv[48][32][2];
  __shared__ float red[8][3];

  const u8* W0   = wb + g * 135168;
  const u8* W1c  = wb + E0 + g * 98304;
  const u8* Wn0p = wb + E1 + g * 16384;
  const u8* Wn1p = wb + E2 + g * 16384;
  const u8* Wm1p = wb + E3 + g * 16384;
  const u8* Wm2p = wb + E4 + g * 16384;
  const u8* WYA  = wb + WYA_REL + aAg * 36864;
  const u8* YBG  = wb + YBG_REL;

  // ---- GRU weights: 57 i64 pinned into AGPRs (114 <= 128) ----
  i64 w0r[11], w0z[11], w0n[7];
#pragma unroll
  for (int kt = 0; kt < 3; ++kt) {
    w0r[kt] = *(const i64*)(WYA + (jh)       * 96 + kt * 32 + kq * 8);
    w0z[kt] = *(const i64*)(WYA + (128 + jh) * 96 + kt * 32 + kq * 8);
    w0n[kt] = *(const i64*)(WYA + (256 + jh) * 96 + kt * 32 + kq * 8);
  }
#pragma unroll
  for (int kt = 3; kt < 11; ++kt) {
    w0r[kt] = *(const i64*)(W0 + (jh)       * 352 + kt * 32 + kq * 8);
    w0z[kt] = *(const i64*)(W0 + (128 + jh) * 352 + kt * 32 + kq * 8);
    if (kt < 7) w0n[kt] = *(const i64*)(W0 + (256 + jh) * 352 + kt * 32 + kq * 8);
  }
  i64 w1r[8], w1z[8], w1n[4];
#pragma unroll
  for (int kt = 0; kt < 8; ++kt) {
    w1r[kt] = *(const i64*)(W1c + (jh)       * 256 + kt * 32 + kq * 8);
    w1z[kt] = *(const i64*)(W1c + (128 + jh) * 256 + kt * 32 + kq * 8);
    if (kt < 4) w1n[kt] = *(const i64*)(W1c + (256 + jh) * 256 + kt * 32 + kq * 8);
  }
  i64 wn0[4], wn1[4];
#pragma unroll
  for (int kt = 0; kt < 4; ++kt) {
    wn0[kt] = *(const i64*)(Wn0p + jh * 128 + kt * 32 + kq * 8);
    wn1[kt] = *(const i64*)(Wn1p + jh * 128 + kt * 32 + kq * 8);
  }
#pragma unroll
  for (int kt = 0; kt < 11; ++kt) { pinA(w0r[kt]); pinA(w0z[kt]); }
#pragma unroll
  for (int kt = 0; kt < 7; ++kt) pinA(w0n[kt]);
#pragma unroll
  for (int kt = 0; kt < 8; ++kt) { pinA(w1r[kt]); pinA(w1z[kt]); }
#pragma unroll
  for (int kt = 0; kt < 4; ++kt) { pinA(w1n[kt]); pinA(wn0[kt]); pinA(wn1[kt]); }

  // ---- biases + Wm into LDS ----
  for (int i = tid; i < 1536; i += 512) {
    float v;
    if (i < 256)       v = wsf[4 + g * 256 + i];
    else if (i < 384)  v = wsf[516 + g * 128 + (i - 256)];
    else if (i < 512)  v = wsf[772 + g * 128 + (i - 384)];
    else if (i < 768)  v = wsf[1028 + g * 256 + (i - 512)];
    else if (i < 896)  v = wsf[1540 + g * 128 + (i - 768)];
    else if (i < 1024) v = wsf[1796 + g * 128 + (i - 896)];
    else if (i < 1152) v = b1g[g * 128 + (i - 1024)];
    else if (i < 1280) v = b2g[g * 128 + (i - 1152)];
    else               v = Wmg[g * 256 + (i - 1280)];
    bias[i] = v;
  }
  for (int i = tid; i < 32 * 136; i += 512) { h0b[0][i] = 0; h1b[0][i] = 0; }

  f32x4 hv0[2] = {{0,0,0,0},{0,0,0,0}};
  f32x4 hv1[2] = {{0,0,0,0},{0,0,0,0}};
  __syncthreads();

  for (int t = 0; t < 48; ++t) {
    const int cur = t & 1, nxt = cur ^ 1;
    const u8* h0c = h0b[cur]; u8* h0n = h0b[nxt];
    const u8* h1c = h1b[cur]; u8* h1n = h1b[nxt];

    // ---- P1: y frags (L2) + MLP1 + GRU0 ----
    const u8* yt = YBG + t * 24576;
    i64 yf[3][2];
#pragma unroll
    for (int kt = 0; kt < 3; ++kt) {
      yf[kt][0] = *(const i64*)(yt + (b0 + j_in) * 96 + kt * 32 + kq * 8);
      yf[kt][1] = *(const i64*)(yt + (b0 + 16 + j_in) * 96 + kt * 32 + kq * 8);
    }

    const u8* pH1a = h1c + j_in * 136 + kq * 8;
    const u8* pH1b = h1c + (16 + j_in) * 136 + kq * 8;
    const u8* pH0a = h0c + j_in * 136 + kq * 8;
    const u8* pH0b = h0c + (16 + j_in) * 136 + kq * 8;

    i64 fh1[4][2];
#pragma unroll
    for (int kt = 0; kt < 4; ++kt) {
      fh1[kt][0] = *(const i64*)(pH1a + kt * 32);
      fh1[kt][1] = *(const i64*)(pH1b + kt * 32);
    }

    // MLP1 (wm1 streamed from L2 this phase)
    {
      f32x4 m0 = {0,0,0,0}, m1 = {0,0,0,0};
#pragma unroll
      for (int kt = 0; kt < 4; ++kt) {
        i64 w = *(const i64*)(Wm1p + jh * 128 + kt * 32 + kq * 8);
        MFMA_F8(m0, w, fh1[kt][0]);
        MFMA_F8(m1, w, fh1[kt][1]);
      }
      f32x4 b1v = *(const f32x4*)(bias + 1024 + c0);
      *(u32*)(d1b + j_in * 136 + c0) =
        pk4(fmaxf(m0[0]+b1v[0],0.f), fmaxf(m0[1]+b1v[1],0.f), fmaxf(m0[2]+b1v[2],0.f), fmaxf(m0[3]+b1v[3],0.f));
      *(u32*)(d1b + (16 + j_in) * 136 + c0) =
        pk4(fmaxf(m1[0]+b1v[0],0.f), fmaxf(m1[1]+b1v[1],0.f), fmaxf(m1[2]+b1v[2],0.f), fmaxf(m1[3]+b1v[3],0.f));
    }

    // GRU0
    {
      f32x4 aR[2] = {{0,0,0,0},{0,0,0,0}};
      f32x4 aZ[2] = {{0,0,0,0},{0,0,0,0}};
      f32x4 aN[2] = {{0,0,0,0},{0,0,0,0}};
      f32x4 aG[2] = {{0,0,0,0},{0,0,0,0}};
#pragma unroll
      for (int kt = 0; kt < 11; ++kt) {
        i64 bb0, bb1;
        if (kt < 3)      { bb0 = yf[kt][0];      bb1 = yf[kt][1]; }
        else if (kt < 7) { bb0 = fh1[kt - 3][0]; bb1 = fh1[kt - 3][1]; }
        else             { bb0 = *(const i64*)(pH0a + (kt - 7) * 32);
                           bb1 = *(const i64*)(pH0b + (kt - 7) * 32); }
        MFMA_F8(aR[0], w0r[kt], bb0); MFMA_F8(aR[1], w0r[kt], bb1);
        MFMA_F8(aZ[0], w0z[kt], bb0); MFMA_F8(aZ[1], w0z[kt], bb1);
        if (kt < 7) { MFMA_F8(aN[0], w0n[kt], bb0); MFMA_F8(aN[1], w0n[kt], bb1); }
        else        { MFMA_F8(aG[0], wn0[kt - 7], bb0); MFMA_F8(aG[1], wn0[kt - 7], bb1); }
      }
      f32x4 brv = *(const f32x4*)(bias + c0);
      f32x4 bzv = *(const f32x4*)(bias + 128 + c0);
      f32x4 biv = *(const f32x4*)(bias + 256 + c0);
      f32x4 bhv = *(const f32x4*)(bias + 384 + c0);
#pragma unroll
      for (int nt = 0; nt < 2; ++nt)
#pragma unroll
        for (int i = 0; i < 4; ++i) {
          float rv = sigf(aR[nt][i] + brv[i]);
          float zv = sigf(aZ[nt][i] + bzv[i]);
          float nv = tanh_fast(aN[nt][i] + biv[i] + rv * (aG[nt][i] + bhv[i]));
          hv0[nt][i] = (1.f - zv) * nv + zv * hv0[nt][i];
        }
    }
    __syncthreads(); // B1: d1b ready; h0c/h1c reads done

    // ---- P2: h0 writeback + MLP2 ----
#pragma unroll
    for (int nt = 0; nt < 2; ++nt)
      *(u32*)(h0n + (nt * 16 + j_in) * 136 + c0) = pk4(hv0[nt][0], hv0[nt][1], hv0[nt][2], hv0[nt][3]);
    {
      f32x4 m0 = {0,0,0,0}, m1 = {0,0,0,0};
#pragma unroll
      for (int kt = 0; kt < 4; ++kt) {
        i64 w = *(const i64*)(Wm2p + jh * 128 + kt * 32 + kq * 8);
        i64 bb0 = *(const i64*)(d1b + j_in * 136 + kt * 32 + kq * 8);
        i64 bb1 = *(const i64*)(d1b + (16 + j_in) * 136 + kt * 32 + kq * 8);
        MFMA_F8(m0, w, bb0);
        MFMA_F8(m1, w, bb1);
      }
      f32x4 b2v = *(const f32x4*)(bias + 1152 + c0);
      *(u32*)(d2b + j_in * 136 + c0) =
        pk4(fmaxf(m0[0]+b2v[0],0.f), fmaxf(m0[1]+b2v[1],0.f), fmaxf(m0[2]+b2v[2],0.f), fmaxf(m0[3]+b2v[3],0.f));
      *(u32*)(d2b + (16 + j_in) * 136 + c0) =
        pk4(fmaxf(m1[0]+b2v[0],0.f), fmaxf(m1[1]+b2v[1],0.f), fmaxf(m1[2]+b2v[2],0.f), fmaxf(m1[3]+b2v[3],0.f));
    }
    __syncthreads(); // B2: h0n + d2b ready

    // ---- P3: GRU1 + dm + h1 writeback ----
    {
      f32x4 aR[2] = {{0,0,0,0},{0,0,0,0}};
      f32x4 aZ[2] = {{0,0,0,0},{0,0,0,0}};
      f32x4 aN[2] = {{0,0,0,0},{0,0,0,0}};
      f32x4 aG[2] = {{0,0,0,0},{0,0,0,0}};
      const u8* pG0a = h0n + j_in * 136 + kq * 8;
      const u8* pG0b = h0n + (16 + j_in) * 136 + kq * 8;
#pragma unroll
      for (int kt = 0; kt < 8; ++kt) {
        i64 bb0, bb1;
        if (kt < 4) { bb0 = *(const i64*)(pG0a + kt * 32); bb1 = *(const i64*)(pG0b + kt * 32); }
        else        { bb0 = fh1[kt - 4][0];                bb1 = fh1[kt - 4][1]; }
        MFMA_F8(aR[0], w1r[kt], bb0); MFMA_F8(aR[1], w1r[kt], bb1);
        MFMA_F8(aZ[0], w1z[kt], bb0); MFMA_F8(aZ[1], w1z[kt], bb1);
        if (kt < 4) { MFMA_F8(aN[0], w1n[kt], bb0); MFMA_F8(aN[1], w1n[kt], bb1); }
        else        { MFMA_F8(aG[0], wn1[kt - 4], bb0); MFMA_F8(aG[1], wn1[kt - 4], bb1); }
      }
      // dm partials (reads d2b) while GRU1 MFMAs drain
      {
        int row = tid >> 4, c = (tid >> 3) & 1, part = tid & 7;
        const u8* dp = d2b + row * 136 + part * 16;
        const float* wmr = bias + 1280 + c * 128 + part * 16;
        float s = 0.f;
#pragma unroll
        for (int q = 0; q < 4; ++q) {
          u32 w = *(const u32*)(dp + q * 4);
          s += wmr[q * 4 + 0] * __builtin_amdgcn_cvt_f32_fp8((int)w, 0);
          s += wmr[q * 4 + 1] * __builtin_amdgcn_cvt_f32_fp8((int)w, 1);
          s += wmr[q * 4 + 2] * __builtin_amdgcn_cvt_f32_fp8((int)w, 2);
          s += wmr[q * 4 + 3] * __builtin_amdgcn_cvt_f32_fp8((int)w, 3);
        }
        s += __shfl_xor(s, 1); s += __shfl_xor(s, 2); s += __shfl_xor(s, 4);
        if (part == 0) dmv[t][row][c] = s;
      }
      f32x4 brv = *(const f32x4*)(bias + 512 + c0);
      f32x4 bzv = *(const f32x4*)(bias + 640 + c0);
      f32x4 biv = *(const f32x4*)(bias + 768 + c0);
      f32x4 bhv = *(const f32x4*)(bias + 896 + c0);
#pragma unroll
      for (int nt = 0; nt < 2; ++nt)
#pragma unroll
        for (int i = 0; i < 4; ++i) {
          float rv = sigf(aR[nt][i] + brv[i]);
          float zv = sigf(aZ[nt][i] + bzv[i]);
          float nv = tanh_fast(aN[nt][i] + biv[i] + rv * (aG[nt][i] + bhv[i]));
          hv1[nt][i] = (1.f - zv) * nv + zv * hv1[nt][i];
        }
#pragma unroll
      for (int nt = 0; nt < 2; ++nt)
        *(u32*)(h1n + (nt * 16 + j_in) * 136 + c0) = pk4(hv1[nt][0], hv1[nt][1], hv1[nt][2], hv1[nt][3]);
    }
    __syncthreads(); // B3
  }

  // ---- error phase (post-loop, fully parallel) ----
  float accL = 0.f, accEp = 0.f, accEv = 0.f;
  const float bm0 = bmg[g * 2], bm1 = bmg[g * 2 + 1];
  for (int idx = tid; idx < 1536; idx += 512) {
    int t = idx >> 5, row = idx & 31;
    const float* sr = states + ((size_t)(t * 256 + b0 + row)) * 92 + aAg * 4;
    const float* sn = sr + 256 * 92;
    float dx = dmv[t][row][0] + bm0 - sn[2];
    float dy = dmv[t][row][1] + bm1 - sn[3];
    float e = sqrtf(dx * dx + dy * dy);
    accL += e;
    if (t >= 12) {
      accEv += e;
      float ex = sr[0] + 0.1f * sr[2] - sn[0];
      float ey = sr[1] + 0.1f * sr[3] - sn[1];
      accEp += sqrtf(ex * ex + ey * ey);
    }
  }
#pragma unroll
  for (int k = 1; k < 64; k <<= 1) {
    accL  += __shfl_xor(accL, k);
    accEp += __shfl_xor(accEp, k);
    accEv += __shfl_xor(accEv, k);
  }
  if (ln == 0) { red[wid][0] = accL; red[wid][1] = accEp; red[wid][2] = accEv; }
  __syncthreads();
  if (tid < 3) {
    float s = 0.f;
    for (int i = 0; i < 8; ++i) s += red[i][tid];
    atomicAdd(&wsf[tid], s);
  }
}

__global__ void fin_kernel(const float* __restrict__ wacc, float* __restrict__ out) {
  if (threadIdx.x == 0 && blockIdx.x == 0) {
    out[0] = wacc[0] / 1104.f;
    out[1] = wacc[1] / 828.f;
    out[2] = wacc[2] / 828.f;
  }
}

extern "C" void kernel_launch(void* const* d_in, const int* in_sizes, int n_in,
                              void* d_out, int out_size, void* d_ws, size_t ws_size,
                              hipStream_t stream) {
  const float* states = (const float*)d_in[0];
  const float* Wih0 = (const float*)d_in[1];
  const float* Whh0 = (const float*)d_in[2];
  const float* bih0 = (const float*)d_in[3];
  const float* bhh0 = (const float*)d_in[4];
  const float* Wih1 = (const float*)d_in[5];
  const float* Whh1 = (const float*)d_in[6];
  const float* bih1 = (const float*)d_in[7];
  const float* bhh1 = (const float*)d_in[8];
  const float* W1   = (const float*)d_in[9];
  const float* b1   = (const float*)d_in[10];
  const float* W2   = (const float*)d_in[11];
  const float* b2   = (const float*)d_in[12];
  const float* Wm   = (const float*)d_in[13];
  const float* bm   = (const float*)d_in[14];

  float* wsf = (float*)d_ws;
  u8* wb = (u8*)d_ws + WB_BYTE_OFF;

  int prep_blocks = (NA3 + 255) / 256;
  if (prep_blocks > 2048) prep_blocks = 2048;
  prep_kernel<<<prep_blocks, 256, 0, stream>>>(states, Wih0, Whh0, bih0, bhh0,
                                               Wih1, Whh1, bih1, bhh1,
                                               W1, W2, wb, wsf);
  rnn_kernel<<<184, 512, 0, stream>>>(states, wb, wsf, b1, b2, Wm, bm);
  fin_kernel<<<1, 64, 0, stream>>>(wsf, (float*)d_out);
}

// Round 10
// 315.069 us; speedup vs baseline: 1.1340x; 1.1340x over previous
//
#include <hip/hip_runtime.h>
#include <hip/hip_bf16.h>

// RNN_41807211659578 R10: R5 exact structure (65 weight i64 pinned "+v" —
// the only verified spill-free config, 252us) + single delta: y staging
// replaced by WYA (vel folded into per-agent weights) + YBG (pre-packed
// fp8 y in global, read as B-frags from L2).

typedef unsigned short u16;
typedef unsigned int u32;
typedef unsigned char u8;
typedef long i64;
typedef __attribute__((ext_vector_type(4))) float f32x4;

#define MFMA_F8(acc, a, b) (acc) = __builtin_amdgcn_mfma_f32_16x16x32_fp8_fp8((i64)(a), (i64)(b), (acc), 0, 0, 0)

__device__ __forceinline__ void pinV(i64& x) { asm volatile("" : "+v"(x)); }

__device__ __forceinline__ u8 f2e4(float v) {
  return (u8)(__builtin_amdgcn_cvt_pk_fp8_f32(v, 0.f, 0, false) & 0xff);
}
__device__ __forceinline__ u32 pk4(float a, float b, float c, float d) {
  u32 p = (u32)__builtin_amdgcn_cvt_pk_fp8_f32(a, b, 0, false);
  return (u32)__builtin_amdgcn_cvt_pk_fp8_f32(c, d, (int)p, true);
}
__device__ __forceinline__ float sigf(float x) {
  return __builtin_amdgcn_rcpf(1.f + __expf(-x));
}
__device__ __forceinline__ float tanh_fast(float x) {
  return 1.f - 2.f * __builtin_amdgcn_rcpf(1.f + __expf(2.f * x));
}

// ---- workspace layout ----
constexpr int E0 = 2 * 384 * 352;      // W0cat [g][384][352] fp8
constexpr int E1 = E0 + 2 * 384 * 256; // W1cat [g][384][256]
constexpr int E2 = E1 + 2 * 128 * 128; // Wn0 (Whh0 n-rows)
constexpr int E3 = E2 + 2 * 128 * 128; // Wn1
constexpr int E4 = E3 + 2 * 128 * 128; // Wm1 (MLP W1)
constexpr int E5 = E4 + 2 * 128 * 128; // Wm2 (MLP W2)
constexpr int NBIAS = 2048;
constexpr int TOTAL = E5 + NBIAS + 4;
constexpr int WB_BYTE_OFF = 16384;

constexpr int WYA_REL = E5;                      // per-agent folded y-weights [23][384][96]
constexpr int YBG_REL = WYA_REL + 23 * 384 * 96; // packed y fp8 [48][256][96]
constexpr int NA1 = TOTAL;
constexpr int NA2 = NA1 + 23 * 384 * 96;
constexpr int NA3 = NA2 + 48 * 256 * 96;

__global__ void prep_kernel(const float* __restrict__ states,
                            const float* __restrict__ Wih0, const float* __restrict__ Whh0,
                            const float* __restrict__ bih0, const float* __restrict__ bhh0,
                            const float* __restrict__ Wih1, const float* __restrict__ Whh1,
                            const float* __restrict__ bih1, const float* __restrict__ bhh1,
                            const float* __restrict__ W1, const float* __restrict__ W2,
                            u8* __restrict__ wb, float* __restrict__ wsf) {
  for (int idx = blockIdx.x * blockDim.x + threadIdx.x; idx < NA3;
       idx += gridDim.x * blockDim.x) {
    if (idx < E0) {
      int g = idx / 135168;
      int r = idx - g * 135168;
      int j = r / 352;
      int k = r - j * 352;
      const float* wi = Wih0 + (g * 384 + j) * 222;
      float v;
      if (k < 94) v = wi[k];
      else if (k < 96) v = 0.f;
      else if (k < 224) v = wi[k - 2];
      else v = Whh0[(g * 384 + j) * 128 + (k - 224)];
      wb[idx] = f2e4(v);
    } else if (idx < E1) {
      int q = idx - E0;
      int g = q / 98304;
      int r = q - g * 98304;
      int j = r >> 8;
      int k = r & 255;
      float v = (k < 128) ? Wih1[(g * 384 + j) * 128 + k]
                          : Whh1[(g * 384 + j) * 128 + (k - 128)];
      wb[idx] = f2e4(v);
    } else if (idx < E2) {
      int q = idx - E1; int g = q >> 14; int r = q & 16383; int j = r >> 7; int k = r & 127;
      wb[idx] = f2e4(Whh0[(g * 384 + 256 + j) * 128 + k]);
    } else if (idx < E3) {
      int q = idx - E2; int g = q >> 14; int r = q & 16383; int j = r >> 7; int k = r & 127;
      wb[idx] = f2e4(Whh1[(g * 384 + 256 + j) * 128 + k]);
    } else if (idx < E4) {
      int q = idx - E3; int g = q >> 14; int r = q & 16383; int j = r >> 7; int k = r & 127;
      wb[idx] = f2e4(W1[(g * 128 + j) * 128 + k]);
    } else if (idx < E5) {
      int q = idx - E4; int g = q >> 14; int r = q & 16383; int j = r >> 7; int k = r & 127;
      wb[idx] = f2e4(W2[(g * 128 + j) * 128 + k]);
    } else if (idx < E5 + NBIAS) {
      int q = idx - E5;
      float v;
      if (q < 512)       { int g = q >> 8, j = q & 255;              v = bih0[g*384 + j] + bhh0[g*384 + j]; }
      else if (q < 768)  { int p = q - 512;  int g = p >> 7, j = p & 127; v = bih0[g*384 + 256 + j]; }
      else if (q < 1024) { int p = q - 768;  int g = p >> 7, j = p & 127; v = bhh0[g*384 + 256 + j]; }
      else if (q < 1536) { int p = q - 1024; int g = p >> 8, j = p & 255; v = bih1[g*384 + j] + bhh1[g*384 + j]; }
      else if (q < 1792) { int p = q - 1536; int g = p >> 7, j = p & 127; v = bih1[g*384 + 256 + j]; }
      else               { int p = q - 1792; int g = p >> 7, j = p & 127; v = bhh1[g*384 + 256 + j]; }
      wsf[4 + q] = v;
    } else if (idx < TOTAL) {
      wsf[idx - (E5 + NBIAS)] = 0.f;
    } else if (idx < NA2) {
      // WYA: per-agent folded y-weights [a][j][k], k<96
      int q = idx - NA1;
      int a = q / 36864;
      int r = q - a * 36864;
      int j = r / 96;
      int k = r - j * 96;
      const float* wi = Wih0 + (((a >= 12) ? 1 : 0) * 384 + j) * 222;
      float v = (k < 92) ? wi[2 + k] : 0.f;
      if (k == a * 4 + 2) v += wi[0];
      if (k == a * 4 + 3) v += wi[1];
      wb[WYA_REL + q] = f2e4(v);
    } else {
      // YBG: packed y fp8 [t][row][k], k<96
      int q = idx - NA2;
      int t = q / 24576;
      int r = q - t * 24576;
      int row = r / 96;
      int k = r - row * 96;
      float v = (k < 92) ? states[((size_t)t * 256 + row) * 92 + k] : 0.f;
      wb[YBG_REL + q] = f2e4(v);
    }
  }
}

__global__ __launch_bounds__(512, 2) __attribute__((amdgpu_waves_per_eu(2, 2)))
void rnn_kernel(const float* __restrict__ states,
                const u8* __restrict__ wb,
                float* __restrict__ wsf,
                const float* __restrict__ b1g,
                const float* __restrict__ b2g,
                const float* __restrict__ Wmg,
                const float* __restrict__ bmg) {
  const int blk = blockIdx.x;
  const int g = (blk < 96) ? 0 : 1;
  const int r0 = (g == 0) ? (blk * 32) : ((blk - 96) * 32);
  const int aAg = (g == 0 ? 0 : 12) + (r0 >> 8);
  const int b0 = r0 & 255;

  const int tid = threadIdx.x;
  const int wid = tid >> 6;
  const int ln = tid & 63;
  const int j_in = ln & 15;
  const int kq = ln >> 4;
  const int c0 = wid * 16 + kq * 4;
  const int jh = wid * 16 + j_in;

  __shared__ __align__(16) u8 h0b[2][32 * 136];
  __shared__ __align__(16) u8 h1b[2][32 * 136];
  __shared__ __align__(16) u8 d1b[32 * 136];
  __shared__ __align__(16) u8 d2b[32 * 136];
  __shared__ __align__(16) float bias[1536];
  __shared__ float dmv[48][32][2];
  __shared__ float red[8][3];

  const u8* W0   = wb + g * 135168;
  const u8* W1c  = wb + E0 + g * 98304;
  const u8* Wn0p = wb + E1 + g * 16384;
  const u8* Wn1p = wb + E2 + g * 16384;
  const u8* Wm1p = wb + E3 + g * 16384;
  const u8* Wm2p = wb + E4 + g * 16384;
  const u8* WYA  = wb + WYA_REL + aAg * 36864;
  const u8* YBG  = wb + YBG_REL;

  // ---- weights: 65 i64, "+v" opaque pins (allocator chooses AGPR/VGPR) ----
  i64 w0r[11], w0z[11], w0n[7];
#pragma unroll
  for (int kt = 0; kt < 3; ++kt) {
    w0r[kt] = *(const i64*)(WYA + (jh)       * 96 + kt * 32 + kq * 8);
    w0z[kt] = *(const i64*)(WYA + (128 + jh) * 96 + kt * 32 + kq * 8);
    w0n[kt] = *(const i64*)(WYA + (256 + jh) * 96 + kt * 32 + kq * 8);
  }
#pragma unroll
  for (int kt = 3; kt < 11; ++kt) {
    w0r[kt] = *(const i64*)(W0 + (jh)       * 352 + kt * 32 + kq * 8);
    w0z[kt] = *(const i64*)(W0 + (128 + jh) * 352 + kt * 32 + kq * 8);
    if (kt < 7) w0n[kt] = *(const i64*)(W0 + (256 + jh) * 352 + kt * 32 + kq * 8);
  }
  i64 w1r[8], w1z[8], w1n[4];
#pragma unroll
  for (int kt = 0; kt < 8; ++kt) {
    w1r[kt] = *(const i64*)(W1c + (jh)       * 256 + kt * 32 + kq * 8);
    w1z[kt] = *(const i64*)(W1c + (128 + jh) * 256 + kt * 32 + kq * 8);
    if (kt < 4) w1n[kt] = *(const i64*)(W1c + (256 + jh) * 256 + kt * 32 + kq * 8);
  }
  i64 wn0[4], wn1[4], wm1[4], wm2[4];
#pragma unroll
  for (int kt = 0; kt < 4; ++kt) {
    wn0[kt] = *(const i64*)(Wn0p + jh * 128 + kt * 32 + kq * 8);
    wn1[kt] = *(const i64*)(Wn1p + jh * 128 + kt * 32 + kq * 8);
    wm1[kt] = *(const i64*)(Wm1p + jh * 128 + kt * 32 + kq * 8);
    wm2[kt] = *(const i64*)(Wm2p + jh * 128 + kt * 32 + kq * 8);
  }
#pragma unroll
  for (int kt = 0; kt < 11; ++kt) { pinV(w0r[kt]); pinV(w0z[kt]); }
#pragma unroll
  for (int kt = 0; kt < 7; ++kt) pinV(w0n[kt]);
#pragma unroll
  for (int kt = 0; kt < 8; ++kt) { pinV(w1r[kt]); pinV(w1z[kt]); }
#pragma unroll
  for (int kt = 0; kt < 4; ++kt) {
    pinV(w1n[kt]); pinV(wn0[kt]); pinV(wn1[kt]); pinV(wm1[kt]); pinV(wm2[kt]);
  }

  // ---- biases + Wm into LDS ----
  for (int i = tid; i < 1536; i += 512) {
    float v;
    if (i < 256)       v = wsf[4 + g * 256 + i];
    else if (i < 384)  v = wsf[516 + g * 128 + (i - 256)];
    else if (i < 512)  v = wsf[772 + g * 128 + (i - 384)];
    else if (i < 768)  v = wsf[1028 + g * 256 + (i - 512)];
    else if (i < 896)  v = wsf[1540 + g * 128 + (i - 768)];
    else if (i < 1024) v = wsf[1796 + g * 128 + (i - 896)];
    else if (i < 1152) v = b1g[g * 128 + (i - 1024)];
    else if (i < 1280) v = b2g[g * 128 + (i - 1152)];
    else               v = Wmg[g * 256 + (i - 1280)];
    bias[i] = v;
  }
  for (int i = tid; i < 32 * 136; i += 512) { h0b[0][i] = 0; h1b[0][i] = 0; }

  f32x4 hv0[2] = {{0,0,0,0},{0,0,0,0}};
  f32x4 hv1[2] = {{0,0,0,0},{0,0,0,0}};
  __syncthreads();

  for (int t = 0; t < 48; ++t) {
    const int cur = t & 1, nxt = cur ^ 1;
    const u8* h0c = h0b[cur]; u8* h0n = h0b[nxt];
    const u8* h1c = h1b[cur]; u8* h1n = h1b[nxt];

    // ---- P1: y frags (L2) + MLP1 + GRU0 ----
    const u8* yt = YBG + t * 24576;
    i64 yf[3][2];
#pragma unroll
    for (int kt = 0; kt < 3; ++kt) {
      yf[kt][0] = *(const i64*)(yt + (b0 + j_in) * 96 + kt * 32 + kq * 8);
      yf[kt][1] = *(const i64*)(yt + (b0 + 16 + j_in) * 96 + kt * 32 + kq * 8);
    }

    const u8* pH1a = h1c + j_in * 136 + kq * 8;
    const u8* pH1b = h1c + (16 + j_in) * 136 + kq * 8;
    const u8* pH0a = h0c + j_in * 136 + kq * 8;
    const u8* pH0b = h0c + (16 + j_in) * 136 + kq * 8;

    i64 fh1[4][2];
#pragma unroll
    for (int kt = 0; kt < 4; ++kt) {
      fh1[kt][0] = *(const i64*)(pH1a + kt * 32);
      fh1[kt][1] = *(const i64*)(pH1b + kt * 32);
    }

    // MLP1
    {
      f32x4 m0 = {0,0,0,0}, m1 = {0,0,0,0};
#pragma unroll
      for (int kt = 0; kt < 4; ++kt) {
        MFMA_F8(m0, wm1[kt], fh1[kt][0]);
        MFMA_F8(m1, wm1[kt], fh1[kt][1]);
      }
      f32x4 b1v = *(const f32x4*)(bias + 1024 + c0);
      *(u32*)(d1b + j_in * 136 + c0) =
        pk4(fmaxf(m0[0]+b1v[0],0.f), fmaxf(m0[1]+b1v[1],0.f), fmaxf(m0[2]+b1v[2],0.f), fmaxf(m0[3]+b1v[3],0.f));
      *(u32*)(d1b + (16 + j_in) * 136 + c0) =
        pk4(fmaxf(m1[0]+b1v[0],0.f), fmaxf(m1[1]+b1v[1],0.f), fmaxf(m1[2]+b1v[2],0.f), fmaxf(m1[3]+b1v[3],0.f));
    }

    // GRU0
    {
      f32x4 aR[2] = {{0,0,0,0},{0,0,0,0}};
      f32x4 aZ[2] = {{0,0,0,0},{0,0,0,0}};
      f32x4 aN[2] = {{0,0,0,0},{0,0,0,0}};
      f32x4 aG[2] = {{0,0,0,0},{0,0,0,0}};
#pragma unroll
      for (int kt = 0; kt < 11; ++kt) {
        i64 bb0, bb1;
        if (kt < 3)      { bb0 = yf[kt][0];      bb1 = yf[kt][1]; }
        else if (kt < 7) { bb0 = fh1[kt - 3][0]; bb1 = fh1[kt - 3][1]; }
        else             { bb0 = *(const i64*)(pH0a + (kt - 7) * 32);
                           bb1 = *(const i64*)(pH0b + (kt - 7) * 32); }
        MFMA_F8(aR[0], w0r[kt], bb0); MFMA_F8(aR[1], w0r[kt], bb1);
        MFMA_F8(aZ[0], w0z[kt], bb0); MFMA_F8(aZ[1], w0z[kt], bb1);
        if (kt < 7) { MFMA_F8(aN[0], w0n[kt], bb0); MFMA_F8(aN[1], w0n[kt], bb1); }
        else        { MFMA_F8(aG[0], wn0[kt - 7], bb0); MFMA_F8(aG[1], wn0[kt - 7], bb1); }
      }
      f32x4 brv = *(const f32x4*)(bias + c0);
      f32x4 bzv = *(const f32x4*)(bias + 128 + c0);
      f32x4 biv = *(const f32x4*)(bias + 256 + c0);
      f32x4 bhv = *(const f32x4*)(bias + 384 + c0);
#pragma unroll
      for (int nt = 0; nt < 2; ++nt)
#pragma unroll
        for (int i = 0; i < 4; ++i) {
          float rv = sigf(aR[nt][i] + brv[i]);
          float zv = sigf(aZ[nt][i] + bzv[i]);
          float nv = tanh_fast(aN[nt][i] + biv[i] + rv * (aG[nt][i] + bhv[i]));
          hv0[nt][i] = (1.f - zv) * nv + zv * hv0[nt][i];
        }
    }
    __syncthreads(); // B1: d1b ready; h0c/h1c reads done

    // ---- P2: h0 writeback + MLP2 ----
#pragma unroll
    for (int nt = 0; nt < 2; ++nt)
      *(u32*)(h0n + (nt * 16 + j_in) * 136 + c0) = pk4(hv0[nt][0], hv0[nt][1], hv0[nt][2], hv0[nt][3]);
    {
      f32x4 m0 = {0,0,0,0}, m1 = {0,0,0,0};
#pragma unroll
      for (int kt = 0; kt < 4; ++kt) {
        i64 bb0 = *(const i64*)(d1b + j_in * 136 + kt * 32 + kq * 8);
        i64 bb1 = *(const i64*)(d1b + (16 + j_in) * 136 + kt * 32 + kq * 8);
        MFMA_F8(m0, wm2[kt], bb0);
        MFMA_F8(m1, wm2[kt], bb1);
      }
      f32x4 b2v = *(const f32x4*)(bias + 1152 + c0);
      *(u32*)(d2b + j_in * 136 + c0) =
        pk4(fmaxf(m0[0]+b2v[0],0.f), fmaxf(m0[1]+b2v[1],0.f), fmaxf(m0[2]+b2v[2],0.f), fmaxf(m0[3]+b2v[3],0.f));
      *(u32*)(d2b + (16 + j_in) * 136 + c0) =
        pk4(fmaxf(m1[0]+b2v[0],0.f), fmaxf(m1[1]+b2v[1],0.f), fmaxf(m1[2]+b2v[2],0.f), fmaxf(m1[3]+b2v[3],0.f));
    }
    __syncthreads(); // B2: h0n + d2b ready

    // ---- P3: GRU1 + dm + h1 writeback ----
    {
      f32x4 aR[2] = {{0,0,0,0},{0,0,0,0}};
      f32x4 aZ[2] = {{0,0,0,0},{0,0,0,0}};
      f32x4 aN[2] = {{0,0,0,0},{0,0,0,0}};
      f32x4 aG[2] = {{0,0,0,0},{0,0,0,0}};
      const u8* pG0a = h0n + j_in * 136 + kq * 8;
      const u8* pG0b = h0n + (16 + j_in) * 136 + kq * 8;
#pragma unroll
      for (int kt = 0; kt < 8; ++kt) {
        i64 bb0, bb1;
        if (kt < 4) { bb0 = *(const i64*)(pG0a + kt * 32); bb1 = *(const i64*)(pG0b + kt * 32); }
        else        { bb0 = fh1[kt - 4][0];                bb1 = fh1[kt - 4][1]; }
        MFMA_F8(aR[0], w1r[kt], bb0); MFMA_F8(aR[1], w1r[kt], bb1);
        MFMA_F8(aZ[0], w1z[kt], bb0); MFMA_F8(aZ[1], w1z[kt], bb1);
        if (kt < 4) { MFMA_F8(aN[0], w1n[kt], bb0); MFMA_F8(aN[1], w1n[kt], bb1); }
        else        { MFMA_F8(aG[0], wn1[kt - 4], bb0); MFMA_F8(aG[1], wn1[kt - 4], bb1); }
      }
      // dm partials (reads d2b) while GRU1 MFMAs drain
      {
        int row = tid >> 4, c = (tid >> 3) & 1, part = tid & 7;
        const u8* dp = d2b + row * 136 + part * 16;
        const float* wmr = bias + 1280 + c * 128 + part * 16;
        float s = 0.f;
#pragma unroll
        for (int q = 0; q < 4; ++q) {
          u32 w = *(const u32*)(dp + q * 4);
          s += wmr[q * 4 + 0] * __builtin_amdgcn_cvt_f32_fp8((int)w, 0);
          s += wmr[q * 4 + 1] * __builtin_amdgcn_cvt_f32_fp8((int)w, 1);
          s += wmr[q * 4 + 2] * __builtin_amdgcn_cvt_f32_fp8((int)w, 2);
          s += wmr[q * 4 + 3] * __builtin_amdgcn_cvt_f32_fp8((int)w, 3);
        }
        s += __shfl_xor(s, 1); s += __shfl_xor(s, 2); s += __shfl_xor(s, 4);
        if (part == 0) dmv[t][row][c] = s;
      }
      f32x4 brv = *(const f32x4*)(bias + 512 + c0);
      f32x4 bzv = *(const f32x4*)(bias + 640 + c0);
      f32x4 biv = *(const f32x4*)(bias + 768 + c0);
      f32x4 bhv = *(const f32x4*)(bias + 896 + c0);
#pragma unroll
      for (int nt = 0; nt < 2; ++nt)
#pragma unroll
        for (int i = 0; i < 4; ++i) {
          float rv = sigf(aR[nt][i] + brv[i]);
          float zv = sigf(aZ[nt][i] + bzv[i]);
          float nv = tanh_fast(aN[nt][i] + biv[i] + rv * (aG[nt][i] + bhv[i]));
          hv1[nt][i] = (1.f - zv) * nv + zv * hv1[nt][i];
        }
#pragma unroll
      for (int nt = 0; nt < 2; ++nt)
        *(u32*)(h1n + (nt * 16 + j_in) * 136 + c0) = pk4(hv1[nt][0], hv1[nt][1], hv1[nt][2], hv1[nt][3]);
    }
    __syncthreads(); // B3
  }

  // ---- error phase (post-loop, fully parallel) ----
  float accL = 0.f, accEp = 0.f, accEv = 0.f;
  const float bm0 = bmg[g * 2], bm1 = bmg[g * 2 + 1];
  for (int idx = tid; idx < 1536; idx += 512) {
    int t = idx >> 5, row = idx & 31;
    const float* sr = states + ((size_t)(t * 256 + b0 + row)) * 92 + aAg * 4;
    const float* sn = sr + 256 * 92;
    float dx = dmv[t][row][0] + bm0 - sn[2];
    float dy = dmv[t][row][1] + bm1 - sn[3];
    float e = sqrtf(dx * dx + dy * dy);
    accL += e;
    if (t >= 12) {
      accEv += e;
      float ex = sr[0] + 0.1f * sr[2] - sn[0];
      float ey = sr[1] + 0.1f * sr[3] - sn[1];
      accEp += sqrtf(ex * ex + ey * ey);
    }
  }
#pragma unroll
  for (int k = 1; k < 64; k <<= 1) {
    accL  += __shfl_xor(accL, k);
    accEp += __shfl_xor(accEp, k);
    accEv += __shfl_xor(accEv, k);
  }
  if (ln == 0) { red[wid][0] = accL; red[wid][1] = accEp; red[wid][2] = accEv; }
  __syncthreads();
  if (tid < 3) {
    float s = 0.f;
    for (int i = 0; i < 8; ++i) s += red[i][tid];
    atomicAdd(&wsf[tid], s);
  }
}

__global__ void fin_kernel(const float* __restrict__ wacc, float* __restrict__ out) {
  if (threadIdx.x == 0 && blockIdx.x == 0) {
    out[0] = wacc[0] / 1104.f;
    out[1] = wacc[1] / 828.f;
    out[2] = wacc[2] / 828.f;
  }
}

extern "C" void kernel_launch(void* const* d_in, const int* in_sizes, int n_in,
                              void* d_out, int out_size, void* d_ws, size_t ws_size,
                              hipStream_t stream) {
  const float* states = (const float*)d_in[0];
  const float* Wih0 = (const float*)d_in[1];
  const float* Whh0 = (const float*)d_in[2];
  const float* bih0 = (const float*)d_in[3];
  const float* bhh0 = (const float*)d_in[4];
  const float* Wih1 = (const float*)d_in[5];
  const float* Whh1 = (const float*)d_in[6];
  const float* bih1 = (const float*)d_in[7];
  const float* bhh1 = (const float*)d_in[8];
  const float* W1   = (const float*)d_in[9];
  const float* b1   = (const float*)d_in[10];
  const float* W2   = (const float*)d_in[11];
  const float* b2   = (const float*)d_in[12];
  const float* Wm   = (const float*)d_in[13];
  const float* bm   = (const float*)d_in[14];

  float* wsf = (float*)d_ws;
  u8* wb = (u8*)d_ws + WB_BYTE_OFF;

  int prep_blocks = (NA3 + 255) / 256;
  if (prep_blocks > 2048) prep_blocks = 2048;
  prep_kernel<<<prep_blocks, 256, 0, stream>>>(states, Wih0, Whh0, bih0, bhh0,
                                               Wih1, Whh1, bih1, bhh1,
                                               W1, W2, wb, wsf);
  rnn_kernel<<<184, 512, 0, stream>>>(states, wb, wsf, b1, b2, Wm, bm);
  fin_kernel<<<1, 64, 0, stream>>>(wsf, (float*)d_out);
}

// Round 11
// 287.858 us; speedup vs baseline: 1.2412x; 1.0945x over previous
//
#include <hip/hip_runtime.h>
#include <hip/hip_bf16.h>

// RNN_41807211659578 R11: R10 structure + MX-scaled K=128 MFMA
// (mfma_scale_f32_16x16x128_f8f6f4, scales=1.0): 130 -> 34 MFMA/wave/step.
// Weights 17 x i32x8 (136 regs) pinned "+v"; LDS activation stride 144.

typedef unsigned short u16;
typedef unsigned int u32;
typedef unsigned char u8;
typedef __attribute__((ext_vector_type(4))) float f32x4;
typedef __attribute__((ext_vector_type(8))) int i32x8;

#define MFMA128(acc, a, b) \
  (acc) = __builtin_amdgcn_mfma_scale_f32_16x16x128_f8f6f4( \
      (a), (b), (acc), 0, 0, 0, 0x7F7F7F7F, 0, 0x7F7F7F7F)

__device__ __forceinline__ i32x8 ld8(const u8* p) { return *(const i32x8*)p; }
__device__ __forceinline__ void pinV(i32x8& x) { asm volatile("" : "+v"(x)); }

__device__ __forceinline__ u8 f2e4(float v) {
  return (u8)(__builtin_amdgcn_cvt_pk_fp8_f32(v, 0.f, 0, false) & 0xff);
}
__device__ __forceinline__ u32 pk4(float a, float b, float c, float d) {
  u32 p = (u32)__builtin_amdgcn_cvt_pk_fp8_f32(a, b, 0, false);
  return (u32)__builtin_amdgcn_cvt_pk_fp8_f32(c, d, (int)p, true);
}
__device__ __forceinline__ float sigf(float x) {
  return __builtin_amdgcn_rcpf(1.f + __expf(-x));
}
__device__ __forceinline__ float tanh_fast(float x) {
  return 1.f - 2.f * __builtin_amdgcn_rcpf(1.f + __expf(2.f * x));
}

// ---- workspace layout ----
constexpr int E0 = 2 * 384 * 352;      // W0cat [g][384][352] fp8: [y94|pad2|h1_128|h0_128]
constexpr int E1 = E0 + 2 * 384 * 256; // W1cat [g][384][256]: [h0n_128|h1_128]
constexpr int E2 = E1 + 2 * 128 * 128; // (unused legacy Wn0)
constexpr int E3 = E2 + 2 * 128 * 128; // Wm1
constexpr int E4 = E3 + 2 * 128 * 128; // Wm2
constexpr int E5 = E4 + 2 * 128 * 128;
constexpr int NBIAS = 2048;
constexpr int TOTAL = E5 + NBIAS + 4;
constexpr int WB_BYTE_OFF = 16384;

constexpr int WB0A_REL = E5;                        // [23][384][128] y-block, vel folded
constexpr int YBG2_REL = WB0A_REL + 23 * 384 * 128; // [48][256][128] packed y fp8
constexpr int NA1 = TOTAL;
constexpr int NA2 = NA1 + 23 * 384 * 128;
constexpr int NA3 = NA2 + 48 * 256 * 128;

__global__ void prep_kernel(const float* __restrict__ states,
                            const float* __restrict__ Wih0, const float* __restrict__ Whh0,
                            const float* __restrict__ bih0, const float* __restrict__ bhh0,
                            const float* __restrict__ Wih1, const float* __restrict__ Whh1,
                            const float* __restrict__ bih1, const float* __restrict__ bhh1,
                            const float* __restrict__ W1, const float* __restrict__ W2,
                            u8* __restrict__ wb, float* __restrict__ wsf) {
  for (int idx = blockIdx.x * blockDim.x + threadIdx.x; idx < NA3;
       idx += gridDim.x * blockDim.x) {
    if (idx < E0) {
      int g = idx / 135168;
      int r = idx - g * 135168;
      int j = r / 352;
      int k = r - j * 352;
      const float* wi = Wih0 + (g * 384 + j) * 222;
      float v;
      if (k < 94) v = wi[k];
      else if (k < 96) v = 0.f;
      else if (k < 224) v = wi[k - 2];
      else v = Whh0[(g * 384 + j) * 128 + (k - 224)];
      wb[idx] = f2e4(v);
    } else if (idx < E1) {
      int q = idx - E0;
      int g = q / 98304;
      int r = q - g * 98304;
      int j = r >> 8;
      int k = r & 255;
      float v = (k < 128) ? Wih1[(g * 384 + j) * 128 + k]
                          : Whh1[(g * 384 + j) * 128 + (k - 128)];
      wb[idx] = f2e4(v);
    } else if (idx < E2) {
      wb[idx] = 0; // legacy, unused
    } else if (idx < E3) {
      int q = idx - E2; int g = q >> 14; int r = q & 16383; int j = r >> 7; int k = r & 127;
      wb[idx] = f2e4(W1[(g * 128 + j) * 128 + k]);
    } else if (idx < E4) {
      int q = idx - E3; int g = q >> 14; int r = q & 16383; int j = r >> 7; int k = r & 127;
      wb[idx] = f2e4(W2[(g * 128 + j) * 128 + k]);
    } else if (idx < E5) {
      wb[idx] = 0; // legacy, unused
    } else if (idx < E5 + NBIAS) {
      int q = idx - E5;
      float v;
      if (q < 512)       { int g = q >> 8, j = q & 255;              v = bih0[g*384 + j] + bhh0[g*384 + j]; }
      else if (q < 768)  { int p = q - 512;  int g = p >> 7, j = p & 127; v = bih0[g*384 + 256 + j]; }
      else if (q < 1024) { int p = q - 768;  int g = p >> 7, j = p & 127; v = bhh0[g*384 + 256 + j]; }
      else if (q < 1536) { int p = q - 1024; int g = p >> 8, j = p & 255; v = bih1[g*384 + j] + bhh1[g*384 + j]; }
      else if (q < 1792) { int p = q - 1536; int g = p >> 7, j = p & 127; v = bih1[g*384 + 256 + j]; }
      else               { int p = q - 1792; int g = p >> 7, j = p & 127; v = bhh1[g*384 + 256 + j]; }
      wsf[4 + q] = v;
    } else if (idx < TOTAL) {
      wsf[idx - (E5 + NBIAS)] = 0.f;
    } else if (idx < NA2) {
      // WB0A: per-agent y-block [a][j][128], vel folded, zero-padded
      int q = idx - NA1;
      int a = q / 49152;
      int r = q - a * 49152;
      int j = r >> 7;
      int k = r & 127;
      const float* wi = Wih0 + (((a >= 12) ? 1 : 0) * 384 + j) * 222;
      float v = (k < 92) ? wi[2 + k] : 0.f;
      if (k == a * 4 + 2) v += wi[0];
      if (k == a * 4 + 3) v += wi[1];
      wb[WB0A_REL + q] = f2e4(v);
    } else {
      // YBG2: packed y fp8 [t][row][128]
      int q = idx - NA2;
      int t = q >> 15;
      int r = q & 32767;
      int row = r >> 7;
      int k = r & 127;
      float v = (k < 92) ? states[((size_t)t * 256 + row) * 92 + k] : 0.f;
      wb[YBG2_REL + q] = f2e4(v);
    }
  }
}

__global__ __launch_bounds__(512, 2) __attribute__((amdgpu_waves_per_eu(2, 2)))
void rnn_kernel(const float* __restrict__ states,
                const u8* __restrict__ wb,
                float* __restrict__ wsf,
                const float* __restrict__ b1g,
                const float* __restrict__ b2g,
                const float* __restrict__ Wmg,
                const float* __restrict__ bmg) {
  const int blk = blockIdx.x;
  const int g = (blk < 96) ? 0 : 1;
  const int r0 = (g == 0) ? (blk * 32) : ((blk - 96) * 32);
  const int aAg = (g == 0 ? 0 : 12) + (r0 >> 8);
  const int b0 = r0 & 255;

  const int tid = threadIdx.x;
  const int wid = tid >> 6;
  const int ln = tid & 63;
  const int j_in = ln & 15;
  const int kq = ln >> 4;
  const int c0 = wid * 16 + kq * 4;
  const int jh = wid * 16 + j_in;

  __shared__ __align__(16) u8 h0b[2][32 * 144];
  __shared__ __align__(16) u8 h1b[2][32 * 144];
  __shared__ __align__(16) u8 d1b[32 * 144];
  __shared__ __align__(16) u8 d2b[32 * 144];
  __shared__ __align__(16) float bias[1536];
  __shared__ float dmv[48][32][2];
  __shared__ float red[8][3];

  const u8* W0   = wb + g * 135168;          // rows 352: [y96|h1@96|h0@224]
  const u8* W1c  = wb + E0 + g * 98304;      // rows 256: [h0n@0|h1@128]
  const u8* Wm1p = wb + E2 + g * 16384;      // NOTE: Wm1 at E2..E3 region
  const u8* Wm2p = wb + E3 + g * 16384;
  const u8* WB0A = wb + WB0A_REL + aAg * 49152;
  const u8* YBG  = wb + YBG2_REL;

  // ---- weights: 17 i32x8 (136 regs), "+v" pinned ----
  i32x8 w0r0 = ld8(WB0A + jh * 128 + kq * 32);
  i32x8 w0r1 = ld8(W0 + jh * 352 + 96 + kq * 32);
  i32x8 w0r2 = ld8(W0 + jh * 352 + 224 + kq * 32);
  i32x8 w0z0 = ld8(WB0A + (128 + jh) * 128 + kq * 32);
  i32x8 w0z1 = ld8(W0 + (128 + jh) * 352 + 96 + kq * 32);
  i32x8 w0z2 = ld8(W0 + (128 + jh) * 352 + 224 + kq * 32);
  i32x8 w0n0 = ld8(WB0A + (256 + jh) * 128 + kq * 32);
  i32x8 w0n1 = ld8(W0 + (256 + jh) * 352 + 96 + kq * 32);
  i32x8 wn0  = ld8(W0 + (256 + jh) * 352 + 224 + kq * 32);
  i32x8 w1r0 = ld8(W1c + jh * 256 + kq * 32);
  i32x8 w1r1 = ld8(W1c + jh * 256 + 128 + kq * 32);
  i32x8 w1z0 = ld8(W1c + (128 + jh) * 256 + kq * 32);
  i32x8 w1z1 = ld8(W1c + (128 + jh) * 256 + 128 + kq * 32);
  i32x8 w1n0 = ld8(W1c + (256 + jh) * 256 + kq * 32);
  i32x8 wn1  = ld8(W1c + (256 + jh) * 256 + 128 + kq * 32);
  i32x8 wm1  = ld8(Wm1p + jh * 128 + kq * 32);
  i32x8 wm2  = ld8(Wm2p + jh * 128 + kq * 32);
  pinV(w0r0); pinV(w0r1); pinV(w0r2);
  pinV(w0z0); pinV(w0z1); pinV(w0z2);
  pinV(w0n0); pinV(w0n1); pinV(wn0);
  pinV(w1r0); pinV(w1r1); pinV(w1z0); pinV(w1z1);
  pinV(w1n0); pinV(wn1); pinV(wm1); pinV(wm2);

  // ---- biases + Wm into LDS ----
  for (int i = tid; i < 1536; i += 512) {
    float v;
    if (i < 256)       v = wsf[4 + g * 256 + i];
    else if (i < 384)  v = wsf[516 + g * 128 + (i - 256)];
    else if (i < 512)  v = wsf[772 + g * 128 + (i - 384)];
    else if (i < 768)  v = wsf[1028 + g * 256 + (i - 512)];
    else if (i < 896)  v = wsf[1540 + g * 128 + (i - 768)];
    else if (i < 1024) v = wsf[1796 + g * 128 + (i - 896)];
    else if (i < 1152) v = b1g[g * 128 + (i - 1024)];
    else if (i < 1280) v = b2g[g * 128 + (i - 1152)];
    else               v = Wmg[g * 256 + (i - 1280)];
    bias[i] = v;
  }
  for (int i = tid; i < 32 * 144; i += 512) { h0b[0][i] = 0; h1b[0][i] = 0; }

  f32x4 hv0[2] = {{0,0,0,0},{0,0,0,0}};
  f32x4 hv1[2] = {{0,0,0,0},{0,0,0,0}};
  __syncthreads();

  for (int t = 0; t < 48; ++t) {
    const int cur = t & 1, nxt = cur ^ 1;
    const u8* h0c = h0b[cur]; u8* h0n = h0b[nxt];
    const u8* h1c = h1b[cur]; u8* h1n = h1b[nxt];
    const u8* yt = YBG + t * 32768;

    // ---- P1: MLP1 + GRU0 (per-nt sequential to cap liveness) ----
    {
      f32x4 b1v = *(const f32x4*)(bias + 1024 + c0);
      f32x4 brv = *(const f32x4*)(bias + c0);
      f32x4 bzv = *(const f32x4*)(bias + 128 + c0);
      f32x4 biv = *(const f32x4*)(bias + 256 + c0);
      f32x4 bhv = *(const f32x4*)(bias + 384 + c0);
#pragma unroll
      for (int nt = 0; nt < 2; ++nt) {
        const int row = nt * 16 + j_in;
        i32x8 fy  = ld8(yt + (b0 + row) * 128 + kq * 32);
        i32x8 fh1 = ld8(h1c + row * 144 + kq * 32);
        i32x8 fh0 = ld8(h0c + row * 144 + kq * 32);
        f32x4 mm = {0,0,0,0};
        MFMA128(mm, wm1, fh1);
        f32x4 aR = {0,0,0,0}, aZ = {0,0,0,0}, aN = {0,0,0,0}, aG = {0,0,0,0};
        MFMA128(aR, w0r0, fy);  MFMA128(aZ, w0z0, fy);  MFMA128(aN, w0n0, fy);
        MFMA128(aR, w0r1, fh1); MFMA128(aZ, w0z1, fh1); MFMA128(aN, w0n1, fh1);
        MFMA128(aR, w0r2, fh0); MFMA128(aZ, w0z2, fh0); MFMA128(aG, wn0, fh0);
        *(u32*)(d1b + row * 144 + c0) =
          pk4(fmaxf(mm[0]+b1v[0],0.f), fmaxf(mm[1]+b1v[1],0.f),
              fmaxf(mm[2]+b1v[2],0.f), fmaxf(mm[3]+b1v[3],0.f));
#pragma unroll
        for (int i = 0; i < 4; ++i) {
          float rv = sigf(aR[i] + brv[i]);
          float zv = sigf(aZ[i] + bzv[i]);
          float nv = tanh_fast(aN[i] + biv[i] + rv * (aG[i] + bhv[i]));
          hv0[nt][i] = (1.f - zv) * nv + zv * hv0[nt][i];
        }
      }
    }
    __syncthreads(); // B1: d1b ready; h0c/h1c reads done

    // ---- P2: h0 writeback + MLP2 ----
#pragma unroll
    for (int nt = 0; nt < 2; ++nt)
      *(u32*)(h0n + (nt * 16 + j_in) * 144 + c0) = pk4(hv0[nt][0], hv0[nt][1], hv0[nt][2], hv0[nt][3]);
    {
      f32x4 b2v = *(const f32x4*)(bias + 1152 + c0);
#pragma unroll
      for (int nt = 0; nt < 2; ++nt) {
        const int row = nt * 16 + j_in;
        i32x8 fd1 = ld8(d1b + row * 144 + kq * 32);
        f32x4 mm = {0,0,0,0};
        MFMA128(mm, wm2, fd1);
        *(u32*)(d2b + row * 144 + c0) =
          pk4(fmaxf(mm[0]+b2v[0],0.f), fmaxf(mm[1]+b2v[1],0.f),
              fmaxf(mm[2]+b2v[2],0.f), fmaxf(mm[3]+b2v[3],0.f));
      }
    }
    __syncthreads(); // B2: h0n + d2b ready

    // ---- P3: GRU1 + dm + h1 writeback ----
    {
      f32x4 brv = *(const f32x4*)(bias + 512 + c0);
      f32x4 bzv = *(const f32x4*)(bias + 640 + c0);
      f32x4 biv = *(const f32x4*)(bias + 768 + c0);
      f32x4 bhv = *(const f32x4*)(bias + 896 + c0);
#pragma unroll
      for (int nt = 0; nt < 2; ++nt) {
        const int row = nt * 16 + j_in;
        i32x8 fg0 = ld8(h0n + row * 144 + kq * 32);
        i32x8 fh1 = ld8(h1c + row * 144 + kq * 32);
        f32x4 aR = {0,0,0,0}, aZ = {0,0,0,0}, aN = {0,0,0,0}, aG = {0,0,0,0};
        MFMA128(aR, w1r0, fg0); MFMA128(aZ, w1z0, fg0); MFMA128(aN, w1n0, fg0);
        MFMA128(aR, w1r1, fh1); MFMA128(aZ, w1z1, fh1); MFMA128(aG, wn1, fh1);
#pragma unroll
        for (int i = 0; i < 4; ++i) {
          float rv = sigf(aR[i] + brv[i]);
          float zv = sigf(aZ[i] + bzv[i]);
          float nv = tanh_fast(aN[i] + biv[i] + rv * (aG[i] + bhv[i]));
          hv1[nt][i] = (1.f - zv) * nv + zv * hv1[nt][i];
        }
        *(u32*)(h1n + row * 144 + c0) = pk4(hv1[nt][0], hv1[nt][1], hv1[nt][2], hv1[nt][3]);
      }
      // dm partials (reads d2b)
      {
        int row = tid >> 4, c = (tid >> 3) & 1, part = tid & 7;
        const u8* dp = d2b + row * 144 + part * 16;
        const float* wmr = bias + 1280 + c * 128 + part * 16;
        float s = 0.f;
#pragma unroll
        for (int q = 0; q < 4; ++q) {
          u32 w = *(const u32*)(dp + q * 4);
          s += wmr[q * 4 + 0] * __builtin_amdgcn_cvt_f32_fp8((int)w, 0);
          s += wmr[q * 4 + 1] * __builtin_amdgcn_cvt_f32_fp8((int)w, 1);
          s += wmr[q * 4 + 2] * __builtin_amdgcn_cvt_f32_fp8((int)w, 2);
          s += wmr[q * 4 + 3] * __builtin_amdgcn_cvt_f32_fp8((int)w, 3);
        }
        s += __shfl_xor(s, 1); s += __shfl_xor(s, 2); s += __shfl_xor(s, 4);
        if (part == 0) dmv[t][row][c] = s;
      }
    }
    __syncthreads(); // B3
  }

  // ---- error phase (post-loop, fully parallel) ----
  float accL = 0.f, accEp = 0.f, accEv = 0.f;
  const float bm0 = bmg[g * 2], bm1 = bmg[g * 2 + 1];
  for (int idx = tid; idx < 1536; idx += 512) {
    int t = idx >> 5, row = idx & 31;
    const float* sr = states + ((size_t)(t * 256 + b0 + row)) * 92 + aAg * 4;
    const float* sn = sr + 256 * 92;
    float dx = dmv[t][row][0] + bm0 - sn[2];
    float dy = dmv[t][row][1] + bm1 - sn[3];
    float e = sqrtf(dx * dx + dy * dy);
    accL += e;
    if (t >= 12) {
      accEv += e;
      float ex = sr[0] + 0.1f * sr[2] - sn[0];
      float ey = sr[1] + 0.1f * sr[3] - sn[1];
      accEp += sqrtf(ex * ex + ey * ey);
    }
  }
#pragma unroll
  for (int k = 1; k < 64; k <<= 1) {
    accL  += __shfl_xor(accL, k);
    accEp += __shfl_xor(accEp, k);
    accEv += __shfl_xor(accEv, k);
  }
  if (ln == 0) { red[wid][0] = accL; red[wid][1] = accEp; red[wid][2] = accEv; }
  __syncthreads();
  if (tid < 3) {
    float s = 0.f;
    for (int i = 0; i < 8; ++i) s += red[i][tid];
    atomicAdd(&wsf[tid], s);
  }
}

__global__ void fin_kernel(const float* __restrict__ wacc, float* __restrict__ out) {
  if (threadIdx.x == 0 && blockIdx.x == 0) {
    out[0] = wacc[0] / 1104.f;
    out[1] = wacc[1] / 828.f;
    out[2] = wacc[2] / 828.f;
  }
}

extern "C" void kernel_launch(void* const* d_in, const int* in_sizes, int n_in,
                              void* d_out, int out_size, void* d_ws, size_t ws_size,
                              hipStream_t stream) {
  const float* states = (const float*)d_in[0];
  const float* Wih0 = (const float*)d_in[1];
  const float* Whh0 = (const float*)d_in[2];
  const float* bih0 = (const float*)d_in[3];
  const float* bhh0 = (const float*)d_in[4];
  const float* Wih1 = (const float*)d_in[5];
  const float* Whh1 = (const float*)d_in[6];
  const float* bih1 = (const float*)d_in[7];
  const float* bhh1 = (const float*)d_in[8];
  const float* W1   = (const float*)d_in[9];
  const float* b1   = (const float*)d_in[10];
  const float* W2   = (const float*)d_in[11];
  const float* b2   = (const float*)d_in[12];
  const float* Wm   = (const float*)d_in[13];
  const float* bm   = (const float*)d_in[14];

  float* wsf = (float*)d_ws;
  u8* wb = (u8*)d_ws + WB_BYTE_OFF;

  int prep_blocks = (NA3 + 255) / 256;
  if (prep_blocks > 2048) prep_blocks = 2048;
  prep_kernel<<<prep_blocks, 256, 0, stream>>>(states, Wih0, Whh0, bih0, bhh0,
                                               Wih1, Whh1, bih1, bhh1,
                                               W1, W2, wb, wsf);
  rnn_kernel<<<184, 512, 0, stream>>>(states, wb, wsf, b1, b2, Wm, bm);
  fin_kernel<<<1, 64, 0, stream>>>(wsf, (float*)d_out);
}

// Round 12
// 285.443 us; speedup vs baseline: 1.2517x; 1.0085x over previous
//
#include <hip/hip_runtime.h>
#include <hip/hip_bf16.h>

// RNN_41807211659578 R12: R11 (MX K=128 MFMA, 207us) + XOR-swizzled LDS
// (stride 160, chunk^(row&3): zero excess conflicts on b256 frag reads)
// + 2 barriers/step (dm deferred one step into P1; fh1 carried across B1).

typedef unsigned short u16;
typedef unsigned int u32;
typedef unsigned char u8;
typedef __attribute__((ext_vector_type(4))) float f32x4;
typedef __attribute__((ext_vector_type(8))) int i32x8;

#define MFMA128(acc, a, b) \
  (acc) = __builtin_amdgcn_mfma_scale_f32_16x16x128_f8f6f4( \
      (a), (b), (acc), 0, 0, 0, 0x7F7F7F7F, 0, 0x7F7F7F7F)

__device__ __forceinline__ i32x8 ld8(const u8* p) { return *(const i32x8*)p; }
__device__ __forceinline__ void pinV(i32x8& x) { asm volatile("" : "+v"(x)); }

__device__ __forceinline__ u8 f2e4(float v) {
  return (u8)(__builtin_amdgcn_cvt_pk_fp8_f32(v, 0.f, 0, false) & 0xff);
}
__device__ __forceinline__ u32 pk4(float a, float b, float c, float d) {
  u32 p = (u32)__builtin_amdgcn_cvt_pk_fp8_f32(a, b, 0, false);
  return (u32)__builtin_amdgcn_cvt_pk_fp8_f32(c, d, (int)p, true);
}
__device__ __forceinline__ float sigf(float x) {
  return __builtin_amdgcn_rcpf(1.f + __expf(-x));
}
__device__ __forceinline__ float tanh_fast(float x) {
  return 1.f - 2.f * __builtin_amdgcn_rcpf(1.f + __expf(2.f * x));
}

// LDS swizzle: stride 160 B/row; 32B chunk c lives at ((c ^ (row&3))*32)
__device__ __forceinline__ int swz256(int row, int kq) {
  return row * 160 + ((kq ^ (row & 3)) << 5);
}
__device__ __forceinline__ int swzU32(int row, int c0) {
  return row * 160 + ((((c0 >> 5) ^ (row & 3)) << 5) | (c0 & 31));
}

// ---- workspace layout (identical to R11) ----
constexpr int E0 = 2 * 384 * 352;
constexpr int E1 = E0 + 2 * 384 * 256;
constexpr int E2 = E1 + 2 * 128 * 128; // Wm1
constexpr int E3 = E2 + 2 * 128 * 128; // Wm2
constexpr int E4 = E3 + 2 * 128 * 128;
constexpr int E5 = E4 + 2 * 128 * 128;
constexpr int NBIAS = 2048;
constexpr int TOTAL = E5 + NBIAS + 4;
constexpr int WB_BYTE_OFF = 16384;

constexpr int WB0A_REL = E5;
constexpr int YBG2_REL = WB0A_REL + 23 * 384 * 128;
constexpr int NA1 = TOTAL;
constexpr int NA2 = NA1 + 23 * 384 * 128;
constexpr int NA3 = NA2 + 48 * 256 * 128;

__global__ void prep_kernel(const float* __restrict__ states,
                            const float* __restrict__ Wih0, const float* __restrict__ Whh0,
                            const float* __restrict__ bih0, const float* __restrict__ bhh0,
                            const float* __restrict__ Wih1, const float* __restrict__ Whh1,
                            const float* __restrict__ bih1, const float* __restrict__ bhh1,
                            const float* __restrict__ W1, const float* __restrict__ W2,
                            u8* __restrict__ wb, float* __restrict__ wsf) {
  for (int idx = blockIdx.x * blockDim.x + threadIdx.x; idx < NA3;
       idx += gridDim.x * blockDim.x) {
    if (idx < E0) {
      int g = idx / 135168;
      int r = idx - g * 135168;
      int j = r / 352;
      int k = r - j * 352;
      const float* wi = Wih0 + (g * 384 + j) * 222;
      float v;
      if (k < 94) v = wi[k];
      else if (k < 96) v = 0.f;
      else if (k < 224) v = wi[k - 2];
      else v = Whh0[(g * 384 + j) * 128 + (k - 224)];
      wb[idx] = f2e4(v);
    } else if (idx < E1) {
      int q = idx - E0;
      int g = q / 98304;
      int r = q - g * 98304;
      int j = r >> 8;
      int k = r & 255;
      float v = (k < 128) ? Wih1[(g * 384 + j) * 128 + k]
                          : Whh1[(g * 384 + j) * 128 + (k - 128)];
      wb[idx] = f2e4(v);
    } else if (idx < E2) {
      int q = idx - E1; int g = q >> 14; int r = q & 16383; int j = r >> 7; int k = r & 127;
      wb[idx] = f2e4(W1[(g * 128 + j) * 128 + k]);
    } else if (idx < E3) {
      int q = idx - E2; int g = q >> 14; int r = q & 16383; int j = r >> 7; int k = r & 127;
      wb[idx] = f2e4(W2[(g * 128 + j) * 128 + k]);
    } else if (idx < E5) {
      wb[idx] = 0;
    } else if (idx < E5 + NBIAS) {
      int q = idx - E5;
      float v;
      if (q < 512)       { int g = q >> 8, j = q & 255;              v = bih0[g*384 + j] + bhh0[g*384 + j]; }
      else if (q < 768)  { int p = q - 512;  int g = p >> 7, j = p & 127; v = bih0[g*384 + 256 + j]; }
      else if (q < 1024) { int p = q - 768;  int g = p >> 7, j = p & 127; v = bhh0[g*384 + 256 + j]; }
      else if (q < 1536) { int p = q - 1024; int g = p >> 8, j = p & 255; v = bih1[g*384 + j] + bhh1[g*384 + j]; }
      else if (q < 1792) { int p = q - 1536; int g = p >> 7, j = p & 127; v = bih1[g*384 + 256 + j]; }
      else               { int p = q - 1792; int g = p >> 7, j = p & 127; v = bhh1[g*384 + 256 + j]; }
      wsf[4 + q] = v;
    } else if (idx < TOTAL) {
      wsf[idx - (E5 + NBIAS)] = 0.f;
    } else if (idx < NA2) {
      int q = idx - NA1;
      int a = q / 49152;
      int r = q - a * 49152;
      int j = r >> 7;
      int k = r & 127;
      const float* wi = Wih0 + (((a >= 12) ? 1 : 0) * 384 + j) * 222;
      float v = (k < 92) ? wi[2 + k] : 0.f;
      if (k == a * 4 + 2) v += wi[0];
      if (k == a * 4 + 3) v += wi[1];
      wb[WB0A_REL + q] = f2e4(v);
    } else {
      int q = idx - NA2;
      int t = q >> 15;
      int r = q & 32767;
      int row = r >> 7;
      int k = r & 127;
      float v = (k < 92) ? states[((size_t)t * 256 + row) * 92 + k] : 0.f;
      wb[YBG2_REL + q] = f2e4(v);
    }
  }
}

__global__ __launch_bounds__(512, 2) __attribute__((amdgpu_waves_per_eu(2, 2)))
void rnn_kernel(const float* __restrict__ states,
                const u8* __restrict__ wb,
                float* __restrict__ wsf,
                const float* __restrict__ b1g,
                const float* __restrict__ b2g,
                const float* __restrict__ Wmg,
                const float* __restrict__ bmg) {
  const int blk = blockIdx.x;
  const int g = (blk < 96) ? 0 : 1;
  const int r0 = (g == 0) ? (blk * 32) : ((blk - 96) * 32);
  const int aAg = (g == 0 ? 0 : 12) + (r0 >> 8);
  const int b0 = r0 & 255;

  const int tid = threadIdx.x;
  const int wid = tid >> 6;
  const int ln = tid & 63;
  const int j_in = ln & 15;
  const int kq = ln >> 4;
  const int c0 = wid * 16 + kq * 4;
  const int jh = wid * 16 + j_in;

  __shared__ __align__(16) u8 h0b[2][32 * 160];
  __shared__ __align__(16) u8 h1b[2][32 * 160];
  __shared__ __align__(16) u8 d1b[32 * 160];
  __shared__ __align__(16) u8 d2b[32 * 160];
  __shared__ __align__(16) float bias[1536];
  __shared__ float dmv[48][32][2];
  __shared__ float red[8][3];

  const u8* W0   = wb + g * 135168;
  const u8* W1c  = wb + E0 + g * 98304;
  const u8* Wm1p = wb + E1 + g * 16384;
  const u8* Wm2p = wb + E2 + g * 16384;
  const u8* WB0A = wb + WB0A_REL + aAg * 49152;
  const u8* YBG  = wb + YBG2_REL;

  // ---- weights: 17 i32x8 (136 regs), "+v" opaque pins ----
  i32x8 w0r0 = ld8(WB0A + jh * 128 + kq * 32);
  i32x8 w0r1 = ld8(W0 + jh * 352 + 96 + kq * 32);
  i32x8 w0r2 = ld8(W0 + jh * 352 + 224 + kq * 32);
  i32x8 w0z0 = ld8(WB0A + (128 + jh) * 128 + kq * 32);
  i32x8 w0z1 = ld8(W0 + (128 + jh) * 352 + 96 + kq * 32);
  i32x8 w0z2 = ld8(W0 + (128 + jh) * 352 + 224 + kq * 32);
  i32x8 w0n0 = ld8(WB0A + (256 + jh) * 128 + kq * 32);
  i32x8 w0n1 = ld8(W0 + (256 + jh) * 352 + 96 + kq * 32);
  i32x8 wn0  = ld8(W0 + (256 + jh) * 352 + 224 + kq * 32);
  i32x8 w1r0 = ld8(W1c + jh * 256 + kq * 32);
  i32x8 w1r1 = ld8(W1c + jh * 256 + 128 + kq * 32);
  i32x8 w1z0 = ld8(W1c + (128 + jh) * 256 + kq * 32);
  i32x8 w1z1 = ld8(W1c + (128 + jh) * 256 + 128 + kq * 32);
  i32x8 w1n0 = ld8(W1c + (256 + jh) * 256 + kq * 32);
  i32x8 wn1  = ld8(W1c + (256 + jh) * 256 + 128 + kq * 32);
  i32x8 wm1  = ld8(Wm1p + jh * 128 + kq * 32);
  i32x8 wm2  = ld8(Wm2p + jh * 128 + kq * 32);
  pinV(w0r0); pinV(w0r1); pinV(w0r2);
  pinV(w0z0); pinV(w0z1); pinV(w0z2);
  pinV(w0n0); pinV(w0n1); pinV(wn0);
  pinV(w1r0); pinV(w1r1); pinV(w1z0); pinV(w1z1);
  pinV(w1n0); pinV(wn1); pinV(wm1); pinV(wm2);

  // ---- biases + Wm into LDS ----
  for (int i = tid; i < 1536; i += 512) {
    float v;
    if (i < 256)       v = wsf[4 + g * 256 + i];
    else if (i < 384)  v = wsf[516 + g * 128 + (i - 256)];
    else if (i < 512)  v = wsf[772 + g * 128 + (i - 384)];
    else if (i < 768)  v = wsf[1028 + g * 256 + (i - 512)];
    else if (i < 896)  v = wsf[1540 + g * 128 + (i - 768)];
    else if (i < 1024) v = wsf[1796 + g * 128 + (i - 896)];
    else if (i < 1152) v = b1g[g * 128 + (i - 1024)];
    else if (i < 1280) v = b2g[g * 128 + (i - 1152)];
    else               v = Wmg[g * 256 + (i - 1280)];
    bias[i] = v;
  }
  for (int i = tid; i < 32 * 160; i += 512) { h0b[0][i] = 0; h1b[0][i] = 0; }

  f32x4 hv0[2] = {{0,0,0,0},{0,0,0,0}};
  f32x4 hv1[2] = {{0,0,0,0},{0,0,0,0}};
  __syncthreads();

  for (int t = 0; t < 48; ++t) {
    const int cur = t & 1, nxt = cur ^ 1;
    const u8* h0c = h0b[cur]; u8* h0n = h0b[nxt];
    const u8* h1c = h1b[cur]; u8* h1n = h1b[nxt];
    const u8* yt = YBG + t * 32768;

    // ==== P1: MLP1 + GRU0 (+h0n write) + dm(t-1) ====
    i32x8 fh1k[2]; // carried to P2 for GRU1
    {
      f32x4 b1v = *(const f32x4*)(bias + 1024 + c0);
      f32x4 brv = *(const f32x4*)(bias + c0);
      f32x4 bzv = *(const f32x4*)(bias + 128 + c0);
      f32x4 biv = *(const f32x4*)(bias + 256 + c0);
      f32x4 bhv = *(const f32x4*)(bias + 384 + c0);
#pragma unroll
      for (int nt = 0; nt < 2; ++nt) {
        const int row = nt * 16 + j_in;
        i32x8 fy  = ld8(yt + (b0 + row) * 128 + kq * 32);
        i32x8 fh1 = ld8(h1c + swz256(row, kq));
        i32x8 fh0 = ld8(h0c + swz256(row, kq));
        fh1k[nt] = fh1;
        f32x4 mm = {0,0,0,0};
        MFMA128(mm, wm1, fh1);
        f32x4 aR = {0,0,0,0}, aZ = {0,0,0,0}, aN = {0,0,0,0}, aG = {0,0,0,0};
        MFMA128(aR, w0r0, fy);  MFMA128(aZ, w0z0, fy);  MFMA128(aN, w0n0, fy);
        MFMA128(aR, w0r1, fh1); MFMA128(aZ, w0z1, fh1); MFMA128(aN, w0n1, fh1);
        MFMA128(aR, w0r2, fh0); MFMA128(aZ, w0z2, fh0); MFMA128(aG, wn0, fh0);
        *(u32*)(d1b + swzU32(row, c0)) =
          pk4(fmaxf(mm[0]+b1v[0],0.f), fmaxf(mm[1]+b1v[1],0.f),
              fmaxf(mm[2]+b1v[2],0.f), fmaxf(mm[3]+b1v[3],0.f));
#pragma unroll
        for (int i = 0; i < 4; ++i) {
          float rv = sigf(aR[i] + brv[i]);
          float zv = sigf(aZ[i] + bzv[i]);
          float nv = tanh_fast(aN[i] + biv[i] + rv * (aG[i] + bhv[i]));
          hv0[nt][i] = (1.f - zv) * nv + zv * hv0[nt][i];
        }
        *(u32*)(h0n + swzU32(row, c0)) = pk4(hv0[nt][0], hv0[nt][1], hv0[nt][2], hv0[nt][3]);
      }
    }
    // dm(t-1): reads d2b written in P2 of t-1 (separated by B2)
    if (t > 0) {
      int row = tid >> 4, c = (tid >> 3) & 1, part = tid & 7;
      const float* wmr = bias + 1280 + c * 128 + part * 16;
      float s = 0.f;
#pragma unroll
      for (int q = 0; q < 4; ++q) {
        u32 w = *(const u32*)(d2b + swzU32(row, part * 16 + q * 4));
        s += wmr[q * 4 + 0] * __builtin_amdgcn_cvt_f32_fp8((int)w, 0);
        s += wmr[q * 4 + 1] * __builtin_amdgcn_cvt_f32_fp8((int)w, 1);
        s += wmr[q * 4 + 2] * __builtin_amdgcn_cvt_f32_fp8((int)w, 2);
        s += wmr[q * 4 + 3] * __builtin_amdgcn_cvt_f32_fp8((int)w, 3);
      }
      s += __shfl_xor(s, 1); s += __shfl_xor(s, 2); s += __shfl_xor(s, 4);
      if (part == 0) dmv[t - 1][row][c] = s;
    }
    __syncthreads(); // B1: d1b + h0n ready; all reads of h0c/h1c/d2b done

    // ==== P2: MLP2 + GRU1 (+h1n write) ====
    {
      f32x4 b2v = *(const f32x4*)(bias + 1152 + c0);
      f32x4 brv = *(const f32x4*)(bias + 512 + c0);
      f32x4 bzv = *(const f32x4*)(bias + 640 + c0);
      f32x4 biv = *(const f32x4*)(bias + 768 + c0);
      f32x4 bhv = *(const f32x4*)(bias + 896 + c0);
#pragma unroll
      for (int nt = 0; nt < 2; ++nt) {
        const int row = nt * 16 + j_in;
        i32x8 fd1 = ld8(d1b + swz256(row, kq));
        i32x8 fg0 = ld8(h0n + swz256(row, kq));
        f32x4 mm = {0,0,0,0};
        MFMA128(mm, wm2, fd1);
        f32x4 aR = {0,0,0,0}, aZ = {0,0,0,0}, aN = {0,0,0,0}, aG = {0,0,0,0};
        MFMA128(aR, w1r0, fg0);      MFMA128(aZ, w1z0, fg0);      MFMA128(aN, w1n0, fg0);
        MFMA128(aR, w1r1, fh1k[nt]); MFMA128(aZ, w1z1, fh1k[nt]); MFMA128(aG, wn1, fh1k[nt]);
        *(u32*)(d2b + swzU32(row, c0)) =
          pk4(fmaxf(mm[0]+b2v[0],0.f), fmaxf(mm[1]+b2v[1],0.f),
              fmaxf(mm[2]+b2v[2],0.f), fmaxf(mm[3]+b2v[3],0.f));
#pragma unroll
        for (int i = 0; i < 4; ++i) {
          float rv = sigf(aR[i] + brv[i]);
          float zv = sigf(aZ[i] + bzv[i]);
          float nv = tanh_fast(aN[i] + biv[i] + rv * (aG[i] + bhv[i]));
          hv1[nt][i] = (1.f - zv) * nv + zv * hv1[nt][i];
        }
        *(u32*)(h1n + swzU32(row, c0)) = pk4(hv1[nt][0], hv1[nt][1], hv1[nt][2], hv1[nt][3]);
      }
    }
    __syncthreads(); // B2: d2b + h1n ready
  }

  // ==== tail: dm(47) ====
  {
    int row = tid >> 4, c = (tid >> 3) & 1, part = tid & 7;
    const float* wmr = bias + 1280 + c * 128 + part * 16;
    float s = 0.f;
#pragma unroll
    for (int q = 0; q < 4; ++q) {
      u32 w = *(const u32*)(d2b + swzU32(row, part * 16 + q * 4));
      s += wmr[q * 4 + 0] * __builtin_amdgcn_cvt_f32_fp8((int)w, 0);
      s += wmr[q * 4 + 1] * __builtin_amdgcn_cvt_f32_fp8((int)w, 1);
      s += wmr[q * 4 + 2] * __builtin_amdgcn_cvt_f32_fp8((int)w, 2);
      s += wmr[q * 4 + 3] * __builtin_amdgcn_cvt_f32_fp8((int)w, 3);
    }
    s += __shfl_xor(s, 1); s += __shfl_xor(s, 2); s += __shfl_xor(s, 4);
    if (part == 0) dmv[47][row][c] = s;
  }
  __syncthreads();

  // ---- error phase (post-loop, fully parallel) ----
  float accL = 0.f, accEp = 0.f, accEv = 0.f;
  const float bm0 = bmg[g * 2], bm1 = bmg[g * 2 + 1];
  for (int idx = tid; idx < 1536; idx += 512) {
    int t = idx >> 5, row = idx & 31;
    const float* sr = states + ((size_t)(t * 256 + b0 + row)) * 92 + aAg * 4;
    const float* sn = sr + 256 * 92;
    float dx = dmv[t][row][0] + bm0 - sn[2];
    float dy = dmv[t][row][1] + bm1 - sn[3];
    float e = sqrtf(dx * dx + dy * dy);
    accL += e;
    if (t >= 12) {
      accEv += e;
      float ex = sr[0] + 0.1f * sr[2] - sn[0];
      float ey = sr[1] + 0.1f * sr[3] - sn[1];
      accEp += sqrtf(ex * ex + ey * ey);
    }
  }
#pragma unroll
  for (int k = 1; k < 64; k <<= 1) {
    accL  += __shfl_xor(accL, k);
    accEp += __shfl_xor(accEp, k);
    accEv += __shfl_xor(accEv, k);
  }
  if (ln == 0) { red[wid][0] = accL; red[wid][1] = accEp; red[wid][2] = accEv; }
  __syncthreads();
  if (tid < 3) {
    float s = 0.f;
    for (int i = 0; i < 8; ++i) s += red[i][tid];
    atomicAdd(&wsf[tid], s);
  }
}

__global__ void fin_kernel(const float* __restrict__ wacc, float* __restrict__ out) {
  if (threadIdx.x == 0 && blockIdx.x == 0) {
    out[0] = wacc[0] / 1104.f;
    out[1] = wacc[1] / 828.f;
    out[2] = wacc[2] / 828.f;
  }
}

extern "C" void kernel_launch(void* const* d_in, const int* in_sizes, int n_in,
                              void* d_out, int out_size, void* d_ws, size_t ws_size,
                              hipStream_t stream) {
  const float* states = (const float*)d_in[0];
  const float* Wih0 = (const float*)d_in[1];
  const float* Whh0 = (const float*)d_in[2];
  const float* bih0 = (const float*)d_in[3];
  const float* bhh0 = (const float*)d_in[4];
  const float* Wih1 = (const float*)d_in[5];
  const float* Whh1 = (const float*)d_in[6];
  const float* bih1 = (const float*)d_in[7];
  const float* bhh1 = (const float*)d_in[8];
  const float* W1   = (const float*)d_in[9];
  const float* b1   = (const float*)d_in[10];
  const float* W2   = (const float*)d_in[11];
  const float* b2   = (const float*)d_in[12];
  const float* Wm   = (const float*)d_in[13];
  const float* bm   = (const float*)d_in[14];

  float* wsf = (float*)d_ws;
  u8* wb = (u8*)d_ws + WB_BYTE_OFF;

  int prep_blocks = (NA3 + 255) / 256;
  if (prep_blocks > 2048) prep_blocks = 2048;
  prep_kernel<<<prep_blocks, 256, 0, stream>>>(states, Wih0, Whh0, bih0, bhh0,
                                               Wih1, Whh1, bih1, bhh1,
                                               W1, W2, wb, wsf);
  rnn_kernel<<<184, 512, 0, stream>>>(states, wb, wsf, b1, b2, Wm, bm);
  fin_kernel<<<1, 64, 0, stream>>>(wsf, (float*)d_out);
}